// Round 5
// baseline (389.499 us; speedup 1.0000x reference)
//
#include <hip/hip_runtime.h>
#include <cstdint>

// ---------- types ----------
typedef float f32x4 __attribute__((ext_vector_type(4)));
typedef __bf16 bf16x8 __attribute__((ext_vector_type(8)));

#define AS1 __attribute__((address_space(1)))
#define AS3 __attribute__((address_space(3)))

__device__ __forceinline__ void gld_lds16(const void* g, void* l) {
    // async global->LDS, 16B per lane; LDS dest = wave-uniform base + lane*16
    __builtin_amdgcn_global_load_lds((const AS1 void*)g, (AS3 void*)l, 16, 0, 0);
}

__device__ __forceinline__ unsigned short f2bf(float f) {  // RNE f32->bf16
    unsigned u = __builtin_bit_cast(unsigned, f);
    u = u + 0x7fffu + ((u >> 16) & 1u);
    return (unsigned short)(u >> 16);
}
__device__ __forceinline__ float bf2f(unsigned short h) {
    unsigned u = ((unsigned)h) << 16;
    return __builtin_bit_cast(float, u);
}

__device__ __forceinline__ void bar() {
    asm volatile("" ::: "memory");
    __builtin_amdgcn_s_barrier();
    asm volatile("" ::: "memory");
}

#define WAITVM(n) asm volatile("s_waitcnt vmcnt(" #n ")" ::: "memory")
#define LGKM0     asm volatile("s_waitcnt lgkmcnt(0)" ::: "memory")
#define SCHED0    __builtin_amdgcn_sched_barrier(0)

// ---------- 8-phase deep-pipelined GEMM: C = A @ B^T, bf16 in, f32 accum ----
// 256xBN tile, BK=64, 8 waves (2M x 4N), per-wave 128 x BN/4 output.
// LDS 2 buffers: A [256 rows][128B] (full-line staging), B [2 ks][BN rows][64B].
// 4 phases per K-tile, phase (mh,ks): 8 ds_read + 1 half-stage + counted vmcnt
// + barrier + lgkmcnt(0) + 16 MFMA + barrier.  Staging schedule (proved safe):
//   ph0: A-H1(t+1)  ph1: B-ks1(t+1)  ph2: B-ks0(t+2)  ph3: A-H0(t+2)
// Every consumer is >=5 phases after its stage; vmcnt window = 4 phases.
// MODE 0: C f32 = acc; 1: +add; 2: bf16 gelu(acc+bias); 3: f32 acc+bias+add
template<int BN, int MODE>
__global__ __launch_bounds__(512, 2) void gemm8p(
    const unsigned short* __restrict__ A, long lda, long sAb,
    const unsigned short* __restrict__ B, long ldb, long sBb,
    void* C, long ldc, long sCb,
    const float* add, long ldadd, long sAddb,
    const float* __restrict__ bias, int K)
{
    constexpr int NR   = BN / 64;          // N-frags per wave
    constexpr int ABUF = 256 * 128;        // 32 KB
    constexpr int BBUF = BN * 128;         // 2 ks-slabs of BN x 64B
    constexpr int BUF  = ABUF + BBUF;
    __shared__ char sm[2 * BUF];
    const int tid = threadIdx.x, lane = tid & 63, wid = tid >> 6;
    const int wr = wid >> 2, wc = wid & 3;  // 2M x 4N wave grid

    const long zb = blockIdx.z;
    // T1: bijective XCD-aware swizzle (m204)
    const int nwg  = gridDim.x * gridDim.y;
    const int orig = blockIdx.y * gridDim.x + blockIdx.x;
    const int q8 = nwg >> 3, r8 = nwg & 7;
    const int xcd = orig & 7;
    const int wg  = (xcd < r8 ? xcd * (q8 + 1) : r8 * (q8 + 1) + (xcd - r8) * q8) + (orig >> 3);
    const int bx = wg % gridDim.x, by = wg / gridDim.x;

    const char* Ab = (const char*)(A + zb * sAb + (long)by * 256 * lda);
    const char* Bb = (const char*)(B + zb * sBb + (long)bx * BN * ldb);
    const long ldaB = lda * 2, ldbB = ldb * 2;

    // stage A half: rows {half*64..+63} and {128+half*64..+63}; full 128B rows,
    // global source chunk pre-swizzled by (row&7); LDS dest linear.
    auto stageA = [&](int kt, int p, int half) {
#pragma unroll
        for (int i = 0; i < 2; ++i) {
            const int r0 = half * 64 + i * 128;
            const int r  = r0 + (tid >> 3);
            gld_lds16(Ab + (long)r * ldaB + (long)kt * 128 + (((tid & 7) ^ (r & 7)) << 4),
                      sm + p * BUF + r0 * 128 + wid * 1024);
        }
    };
    // stage B k-slab ks (BN rows x 64B); source chunk pre-swizzled by ((row>>1)&3)
    auto stageB = [&](int kt, int p, int ks) {
#pragma unroll
        for (int i = 0; i < BN / 128; ++i) {
            const int r = i * 128 + (tid >> 2);
            gld_lds16(Bb + (long)r * ldbB + (long)kt * 128 + ks * 64 + (((tid & 3) ^ ((r >> 1) & 3)) << 4),
                      sm + p * BUF + ABUF + ks * BN * 64 + i * 8192 + wid * 1024);
        }
    };

    f32x4 acc[8][NR] = {};
    const int NT = K / 64;

#define PHASE(MH, KS, STAGE_STMT) do {                                          \
    bf16x8 af[4]; bf16x8 bfr[NR];                                               \
    _Pragma("unroll")                                                           \
    for (int m = 0; m < 4; ++m) {                                               \
        const int R = wr * 128 + ((MH) * 4 + m) * 16 + (lane & 15);             \
        const int cc = (((KS) * 4 + (lane >> 4)) ^ (R & 7)) << 4;               \
        af[m] = *(const bf16x8*)(bufp + R * 128 + cc);                          \
    }                                                                           \
    _Pragma("unroll")                                                           \
    for (int n = 0; n < NR; ++n) {                                              \
        const int R = wc * 16 * NR + n * 16 + (lane & 15);                      \
        const int cc = ((lane >> 4) ^ ((R >> 1) & 3)) << 4;                     \
        bfr[n] = *(const bf16x8*)(bufp + ABUF + (KS) * BN * 64 + R * 64 + cc);  \
    }                                                                           \
    STAGE_STMT;                                                                 \
    if (t < NT - 2) { if constexpr (BN == 256) WAITVM(8); else WAITVM(6); }     \
    else WAITVM(0);                                                             \
    bar();                                                                      \
    LGKM0; SCHED0;                                                              \
    __builtin_amdgcn_s_setprio(1);                                              \
    _Pragma("unroll")                                                           \
    for (int m = 0; m < 4; ++m)                                                 \
    _Pragma("unroll")                                                           \
        for (int n = 0; n < NR; ++n)                                            \
            acc[(MH) * 4 + m][n] = __builtin_amdgcn_mfma_f32_16x16x32_bf16(     \
                af[m], bfr[n], acc[(MH) * 4 + m][n], 0, 0, 0);                  \
    __builtin_amdgcn_s_setprio(0);                                              \
    bar();                                                                      \
} while (0)

    // prologue: tile0 fully, then tile1 ordered {A-H0, B-ks0, A-H1, B-ks1}
    stageA(0, 0, 0); stageA(0, 0, 1); stageB(0, 0, 0); stageB(0, 0, 1);
    stageA(1, 1, 0); stageB(1, 1, 0); stageA(1, 1, 1); stageB(1, 1, 1);
    if constexpr (BN == 256) WAITVM(8); else WAITVM(6);   // tile0 fully landed
    bar();

#pragma unroll 1
    for (int t = 0; t < NT; ++t) {
        const int p = t & 1;
        const char* bufp = sm + p * BUF;
        PHASE(0, 0, { if (t >= 1 && t + 1 < NT) stageA(t + 1, p ^ 1, 1); });
        PHASE(1, 0, { if (t >= 1 && t + 1 < NT) stageB(t + 1, p ^ 1, 1); });
        PHASE(0, 1, { if (t + 2 < NT) stageB(t + 2, p, 0); });
        PHASE(1, 1, { if (t + 2 < NT) stageA(t + 2, p, 0); });
    }
#undef PHASE

    // epilogue: C/D layout col=lane&15, row=(lane>>4)*4+j
    const long row0 = (long)by * 256 + wr * 128 + (lane >> 4) * 4;
    const long col0 = (long)bx * BN + wc * 16 * NR + (lane & 15);
#pragma unroll
    for (int m = 0; m < 8; ++m)
#pragma unroll
        for (int n = 0; n < NR; ++n)
#pragma unroll
            for (int j = 0; j < 4; ++j) {
                const long r = row0 + m * 16 + j;
                const long c = col0 + n * 16;
                const float v = acc[m][n][j];
                if (MODE == 0) {
                    ((float*)C)[zb * sCb + r * ldc + c] = v;
                } else if (MODE == 1) {
                    ((float*)C)[zb * sCb + r * ldc + c] = v + add[zb * sAddb + r * ldadd + c];
                } else if (MODE == 2) {
                    float tt = v + bias[c];
                    float gl = 0.5f * tt * (1.0f + erff(tt * 0.70710678118654752f));
                    ((unsigned short*)C)[zb * sCb + r * ldc + c] = f2bf(gl);
                } else {
                    ((float*)C)[zb * sCb + r * ldc + c] = v + bias[c] + add[zb * sAddb + r * ldadd + c];
                }
            }
}

// ---------- LayerNorm: f32 in -> bf16 out (+ optional sum(y^2), + zero pad) ----------
__global__ __launch_bounds__(256) void ln_kernel(
    const float* __restrict__ x, const float* __restrict__ gamma, const float* __restrict__ beta,
    unsigned short* __restrict__ out, int ldout, float* qout, int pad)
{
    const int tid = threadIdx.x;
    const long row = blockIdx.x;
    float4 v = ((const float4*)(x + row * 1024))[tid];
    float s = v.x + v.y + v.z + v.w;
    float s2 = v.x * v.x + v.y * v.y + v.z * v.z + v.w * v.w;
#pragma unroll
    for (int off = 32; off; off >>= 1) {
        s  += __shfl_down(s, off);
        s2 += __shfl_down(s2, off);
    }
    __shared__ float red[12];
    const int lane = tid & 63, wid = tid >> 6;
    if (lane == 0) { red[wid] = s; red[4 + wid] = s2; }
    __syncthreads();
    s  = red[0] + red[1] + red[2] + red[3];
    s2 = red[4] + red[5] + red[6] + red[7];
    const float mu = s * (1.0f / 1024.0f);
    const float var = s2 * (1.0f / 1024.0f) - mu * mu;
    const float rs = rsqrtf(var + 1e-5f);
    const float4 g = ((const float4*)gamma)[tid];
    const float4 b = ((const float4*)beta)[tid];
    unsigned short o0 = f2bf((v.x - mu) * rs * g.x + b.x);
    unsigned short o1 = f2bf((v.y - mu) * rs * g.y + b.y);
    unsigned short o2 = f2bf((v.z - mu) * rs * g.z + b.z);
    unsigned short o3 = f2bf((v.w - mu) * rs * g.w + b.w);
    ushort4 ov; ov.x = o0; ov.y = o1; ov.z = o2; ov.w = o3;
    ((ushort4*)(out + row * (long)ldout))[tid] = ov;
    if (pad && tid < 32) out[row * (long)ldout + 1056 + tid] = 0;  // zero K-pad
    if (qout) {  // q partial = sum over d of (rounded hn)^2
        float y0 = bf2f(o0), y1 = bf2f(o1), y2 = bf2f(o2), y3 = bf2f(o3);
        float sq = y0 * y0 + y1 * y1 + y2 * y2 + y3 * y3;
#pragma unroll
        for (int off = 32; off; off >>= 1) sq += __shfl_down(sq, off);
        if (lane == 0) red[8 + wid] = sq;
        __syncthreads();
        if (tid == 0) qout[row] = red[8] + red[9] + red[10] + red[11];
    }
}

// ---------- u = hn @ L (r=32), write bf16 into z cols [1024,1056), q += |u|^2 ----------
__global__ __launch_bounds__(256) void u_kernel(
    unsigned short* __restrict__ z, const float* __restrict__ L, float* __restrict__ q)
{
    const int tid = threadIdx.x;
    const long row = blockIdx.x;
    __shared__ float hn[1024];
    __shared__ float part[8][32];
    ushort4 uv = ((const ushort4*)(z + row * 1088))[tid];
    hn[tid * 4 + 0] = bf2f(uv.x);
    hn[tid * 4 + 1] = bf2f(uv.y);
    hn[tid * 4 + 2] = bf2f(uv.z);
    hn[tid * 4 + 3] = bf2f(uv.w);
    __syncthreads();
    const int j = tid & 31, grp = tid >> 5;
    float acc = 0.f;
    const float* Lp = L + j;
#pragma unroll 4
    for (int d = grp * 128; d < grp * 128 + 128; ++d)
        acc += hn[d] * Lp[(long)d * 32];
    part[grp][j] = acc;
    __syncthreads();
    if (tid < 32) {
        float u = 0.f;
#pragma unroll
        for (int g2 = 0; g2 < 8; ++g2) u += part[g2][tid];
        unsigned short ub = f2bf(u);
        z[row * 1088 + 1024 + tid] = ub;
        float uf = bf2f(ub);
        part[0][tid] = uf * uf;
    }
    __syncthreads();
    if (tid == 0) {
        float sq = 0.f;
#pragma unroll
        for (int t2 = 0; t2 < 32; ++t2) sq += part[0][t2];
        q[row] += sq;
    }
}

// ---------- softmax over row: logits = 2*S - q_j; write P bf16 in place ----------
__global__ __launch_bounds__(256) void softmax_kernel(
    float* S, const float* qb)
{
    const int tid = threadIdx.x;
    const long i = blockIdx.x, bl = blockIdx.y;
    float* Sr = S + (bl * 2048 + i) * 2048;
    const float* qr = qb + bl * 2048;
    float l[8];
    float mx = -1e30f;
#pragma unroll
    for (int c2 = 0; c2 < 8; ++c2) {
        const int jj = tid + c2 * 256;
        l[c2] = 2.0f * Sr[jj] - qr[jj];
        mx = fmaxf(mx, l[c2]);
    }
#pragma unroll
    for (int off = 32; off; off >>= 1) mx = fmaxf(mx, __shfl_xor(mx, off));
    __shared__ float red[8];
    const int lane = tid & 63, wid = tid >> 6;
    if (lane == 0) red[wid] = mx;
    __syncthreads();
    mx = fmaxf(fmaxf(red[0], red[1]), fmaxf(red[2], red[3]));
    float sum = 0.f;
#pragma unroll
    for (int c2 = 0; c2 < 8; ++c2) { l[c2] = __expf(l[c2] - mx); sum += l[c2]; }
#pragma unroll
    for (int off = 32; off; off >>= 1) sum += __shfl_xor(sum, off);
    if (lane == 0) red[4 + wid] = sum;
    __syncthreads();
    sum = red[4] + red[5] + red[6] + red[7];
    const float inv = 1.0f / sum;
    unsigned short* Pr = (unsigned short*)S + (bl * 2048 + i) * 4096;  // row stride 8192B
#pragma unroll
    for (int c2 = 0; c2 < 8; ++c2)
        Pr[tid + c2 * 256] = f2bf(l[c2] * inv);
}

// ---------- Vt[b][n][k] = z[b][k][n] (hn part only), bf16 ----------
__global__ __launch_bounds__(256) void transpose_v_kernel(
    const unsigned short* __restrict__ z, unsigned short* __restrict__ Vt, long sVtb)
{
    __shared__ unsigned short t[32][33];
    const int tid = threadIdx.x;
    const int tx = tid & 31, ty = tid >> 5;
    const long b = blockIdx.z;
    const long k0 = (long)blockIdx.x * 32, n0 = (long)blockIdx.y * 32;
#pragma unroll
    for (int r = 0; r < 32; r += 8)
        t[r + ty][tx] = z[(b * 2048 + k0 + r + ty) * 1088 + n0 + tx];
    __syncthreads();
#pragma unroll
    for (int r = 0; r < 32; r += 8)
        Vt[b * sVtb + (n0 + r + ty) * 2048 + k0 + tx] = t[tx][r + ty];
}

// ---------- Wt[c][r] = bf16(W[r][c]) ----------
__global__ __launch_bounds__(256) void cast_transpose_kernel(
    const float* __restrict__ W, unsigned short* __restrict__ Wt, int rows, int cols)
{
    __shared__ float t[32][33];
    const int tid = threadIdx.x;
    const int tx = tid & 31, ty = tid >> 5;
    const long r0 = (long)blockIdx.y * 32, c0 = (long)blockIdx.x * 32;
#pragma unroll
    for (int r = 0; r < 32; r += 8)
        t[r + ty][tx] = W[(r0 + r + ty) * (long)cols + c0 + tx];
    __syncthreads();
#pragma unroll
    for (int r = 0; r < 32; r += 8)
        Wt[(c0 + r + ty) * (long)rows + r0 + tx] = f2bf(t[tx][r + ty]);
}

// ---------- host ----------
// Workspace plan (>= 89.2 MB measured-safe):
//   q    : 32 KB
//   pool : attention overlay  Vt 16.8 | Smat 67.1             (= 83.9 MB)
//          MLP overlay        W1t 8.4 | W2t 8.4 | hm 16.8 | hid 67.1/c
//   z (17.8 MB) lives in d_out (33.5 MB) — dead before PV overwrites it.
extern "C" void kernel_launch(void* const* d_in, const int* in_sizes, int n_in,
                              void* d_out, int out_size, void* d_ws, size_t ws_size,
                              hipStream_t stream)
{
    const float* x   = (const float*)d_in[0];
    const float* L   = (const float*)d_in[1];
    const float* W1  = (const float*)d_in[2];
    const float* b1  = (const float*)d_in[3];
    const float* W2  = (const float*)d_in[4];
    const float* b2  = (const float*)d_in[5];
    const float* g1  = (const float*)d_in[6];
    const float* be1 = (const float*)d_in[7];
    const float* g2  = (const float*)d_in[8];
    const float* be2 = (const float*)d_in[9];
    float* out = (float*)d_out;
    unsigned short* z = (unsigned short*)d_out;     // 8192 x 1088 bf16 in d_out

    char* wsp = (char*)d_ws;
    float* q = (float*)wsp;                          // 32 KB
    char* pool = wsp + 32768;
    // attention overlay
    unsigned short* Vt   = (unsigned short*)pool;                      // 4 x 1024 x 2048 bf16
    float*          Smat = (float*)(pool + 16777216);                  // 4 x 2048 x 2048 f32
    // MLP overlay (valid after PV has consumed Vt/Smat)
    unsigned short* W1t = (unsigned short*)pool;                       // 4096 x 1024 bf16
    unsigned short* W2t = (unsigned short*)(pool + 8388608);           // 1024 x 4096 bf16
    unsigned short* hm  = (unsigned short*)(pool + 16777216);          // 8192 x 1024 bf16
    unsigned short* hid = (unsigned short*)(pool + 33554432);          // 8192 x 4096 bf16 (or /2)
    const bool fullMLP = ws_size >= (size_t)32768 + 100663296 + 65536;

    // LN1 -> z[:,0:1024], q = |hn|^2, zero pad cols 1056:1088
    ln_kernel<<<8192, 256, 0, stream>>>(x, g1, be1, z, 1088, q, 1);
    // u = hn@L -> z[:,1024:1056], q += |u|^2
    u_kernel<<<8192, 256, 0, stream>>>(z, L, q);

    // ---- attention, all 4 batches in parallel ----
    transpose_v_kernel<<<dim3(64, 32, 4), 256, 0, stream>>>(z, Vt, (long)1024 * 2048);
    gemm8p<256, 0><<<dim3(8, 8, 4), 512, 0, stream>>>(
        z, 1088, (long)2048 * 1088,
        z, 1088, (long)2048 * 1088,
        Smat, 2048, (long)2048 * 2048,
        nullptr, 0, 0, nullptr, 1088);
    softmax_kernel<<<dim3(2048, 4), 256, 0, stream>>>(Smat, q);
    gemm8p<128, 1><<<dim3(8, 8, 4), 512, 0, stream>>>(
        (const unsigned short*)Smat, 4096, (long)2048 * 4096,
        Vt, 2048, (long)1024 * 2048,
        out, 1024, (long)2048 * 1024,
        x, 1024, (long)2048 * 1024,
        nullptr, 2048);

    // ---- MLP ----
    cast_transpose_kernel<<<dim3(128, 32), 256, 0, stream>>>(W1, W1t, 1024, 4096);
    cast_transpose_kernel<<<dim3(32, 128), 256, 0, stream>>>(W2, W2t, 4096, 1024);
    ln_kernel<<<8192, 256, 0, stream>>>(out, g2, be2, hm, 1024, nullptr, 0);
    if (fullMLP) {
        gemm8p<256, 2><<<dim3(16, 32, 1), 512, 0, stream>>>(
            hm, 1024, 0, W1t, 1024, 0,
            hid, 4096, 0, nullptr, 0, 0, b1, 1024);
        gemm8p<128, 3><<<dim3(8, 32, 1), 512, 0, stream>>>(
            hid, 4096, 0, W2t, 4096, 0,
            out, 1024, 0, out, 1024, 0, b2, 4096);
    } else {
        for (int c = 0; c < 2; ++c) {
            const unsigned short* hmc = hm + (size_t)c * 4096 * 1024;
            float* oc = out + (size_t)c * 4096 * 1024;
            gemm8p<256, 2><<<dim3(16, 16, 1), 512, 0, stream>>>(
                hmc, 1024, 0, W1t, 1024, 0,
                hid, 4096, 0, nullptr, 0, 0, b1, 1024);
            gemm8p<128, 3><<<dim3(8, 16, 1), 512, 0, stream>>>(
                hid, 4096, 0, W2t, 4096, 0,
                oc, 1024, 0, oc, 1024, 0, b2, 4096);
        }
    }
}

// Round 6
// 375.414 us; speedup vs baseline: 1.0375x; 1.0375x over previous
//
#include <hip/hip_runtime.h>
#include <cstdint>

// ---------- types ----------
typedef float f32x4 __attribute__((ext_vector_type(4)));
typedef __bf16 bf16x8 __attribute__((ext_vector_type(8)));

#define AS1 __attribute__((address_space(1)))
#define AS3 __attribute__((address_space(3)))

__device__ __forceinline__ void gld_lds16(const void* g, void* l) {
    // async global->LDS, 16B per lane; LDS dest = wave-uniform base + lane*16
    __builtin_amdgcn_global_load_lds((const AS1 void*)g, (AS3 void*)l, 16, 0, 0);
}

__device__ __forceinline__ unsigned short f2bf(float f) {  // RNE f32->bf16
    unsigned u = __builtin_bit_cast(unsigned, f);
    u = u + 0x7fffu + ((u >> 16) & 1u);
    return (unsigned short)(u >> 16);
}
__device__ __forceinline__ float bf2f(unsigned short h) {
    unsigned u = ((unsigned)h) << 16;
    return __builtin_bit_cast(float, u);
}

__device__ __forceinline__ void bar() {
    asm volatile("" ::: "memory");
    __builtin_amdgcn_s_barrier();
    asm volatile("" ::: "memory");
}

#define WAITVM(n) asm volatile("s_waitcnt vmcnt(" #n ")" ::: "memory")
#define LGKM0     asm volatile("s_waitcnt lgkmcnt(0)" ::: "memory")
#define SCHED0    __builtin_amdgcn_sched_barrier(0)

// ---------- 8-phase GEMM, per-TILE counted vmcnt: C = A @ B^T, bf16, f32 acc
// 256xBN tile, BK=64, 8 waves (2M x 4N).  LDS 2 buffers:
//   A [256 rows][128B] full-line staging, B [2 ks][BN rows][64B].
// Phase (mh,ks): 8 ds_read + 1 stage + [tile-end: counted vmcnt] + bar
//   + lgkmcnt(0) + 16 MFMA + bar.  Stages: ph0 A-H1(t+1), ph1 B-ks1(t+1),
//   ph2 B-ks0(t+2), ph3 A-H0(t+2).  ONE vmcnt per K-tile (ph3): N = stages
//   issued after tile t+1 completed = ph2+ph3 = 4 (BN=256) / 3 (BN=128).
// SWZ 0: m204 bijective XCD swizzle.  SWZ 1: L2-region map for grid (8,8,4):
//   each XCD owns 4 A-panels x 2 B-panels per batch (3.3 MB <= 4 MB L2).
// MODE 0: C f32 = acc; 1: +add; 2: bf16 gelu(acc+bias); 3: f32 acc+bias+add
template<int BN, int MODE, int SWZ>
__global__ __launch_bounds__(512, 2) void gemm8q(
    const unsigned short* __restrict__ A, long lda, long sAb,
    const unsigned short* __restrict__ B, long ldb, long sBb,
    void* C, long ldc, long sCb,
    const float* add, long ldadd, long sAddb,
    const float* __restrict__ bias, int K)
{
    constexpr int NR   = BN / 64;          // N-frags per wave
    constexpr int ABUF = 256 * 128;        // 32 KB
    constexpr int BBUF = BN * 128;         // 2 ks-slabs of BN x 64B
    constexpr int BUF  = ABUF + BBUF;
    __shared__ char sm[2 * BUF];
    const int tid = threadIdx.x, lane = tid & 63, wid = tid >> 6;
    const int wr = wid >> 2, wc = wid & 3;  // 2M x 4N wave grid

    int bx, by;
    long zb;
    if constexpr (SWZ == 1) {
        // grid must be (8,8,4). HW dispatch index d -> XCD = d&7.
        const int d   = blockIdx.x + ((blockIdx.y + (blockIdx.z << 3)) << 3);
        const int xcd = d & 7, j = d >> 3;
        zb = j >> 3;
        const int pos = j & 7;               // 8 tiles per XCD per batch
        by = ((xcd & 1) << 2) + (pos >> 1);  // 4-row band
        bx = ((xcd >> 1) << 1) + (pos & 1);  // 2-col band
    } else {
        zb = blockIdx.z;
        const int nwg  = gridDim.x * gridDim.y;
        const int orig = blockIdx.y * gridDim.x + blockIdx.x;
        const int q8 = nwg >> 3, r8 = nwg & 7;
        const int xcd = orig & 7;
        const int wg  = (xcd < r8 ? xcd * (q8 + 1) : r8 * (q8 + 1) + (xcd - r8) * q8) + (orig >> 3);
        bx = wg % gridDim.x; by = wg / gridDim.x;
    }

    const char* Ab = (const char*)(A + zb * sAb + (long)by * 256 * lda);
    const char* Bb = (const char*)(B + zb * sBb + (long)bx * BN * ldb);
    const long ldaB = lda * 2, ldbB = ldb * 2;

    // stage A half: rows {half*64..+63} and {128+half*64..+63}; full 128B rows,
    // global source chunk pre-swizzled by (row&7); LDS dest linear.
    auto stageA = [&](int kt, int p, int half) {
#pragma unroll
        for (int i = 0; i < 2; ++i) {
            const int r0 = half * 64 + i * 128;
            const int r  = r0 + (tid >> 3);
            gld_lds16(Ab + (long)r * ldaB + (long)kt * 128 + (((tid & 7) ^ (r & 7)) << 4),
                      sm + p * BUF + r0 * 128 + wid * 1024);
        }
    };
    // stage B k-slab ks (BN rows x 64B); source chunk pre-swizzled by ((row>>1)&3)
    auto stageB = [&](int kt, int p, int ks) {
#pragma unroll
        for (int i = 0; i < BN / 128; ++i) {
            const int r = i * 128 + (tid >> 2);
            gld_lds16(Bb + (long)r * ldbB + (long)kt * 128 + ks * 64 + (((tid & 3) ^ ((r >> 1) & 3)) << 4),
                      sm + p * BUF + ABUF + ks * BN * 64 + i * 8192 + wid * 1024);
        }
    };

    f32x4 acc[8][NR] = {};
    const int NT = K / 64;

#define PHASE(MH, KS, STAGE_STMT, WAIT_STMT) do {                               \
    bf16x8 af[4]; bf16x8 bfr[NR];                                               \
    _Pragma("unroll")                                                           \
    for (int m = 0; m < 4; ++m) {                                               \
        const int R = wr * 128 + ((MH) * 4 + m) * 16 + (lane & 15);             \
        const int cc = (((KS) * 4 + (lane >> 4)) ^ (R & 7)) << 4;               \
        af[m] = *(const bf16x8*)(bufp + R * 128 + cc);                          \
    }                                                                           \
    _Pragma("unroll")                                                           \
    for (int n = 0; n < NR; ++n) {                                              \
        const int R = wc * 16 * NR + n * 16 + (lane & 15);                      \
        const int cc = ((lane >> 4) ^ ((R >> 1) & 3)) << 4;                     \
        bfr[n] = *(const bf16x8*)(bufp + ABUF + (KS) * BN * 64 + R * 64 + cc);  \
    }                                                                           \
    STAGE_STMT;                                                                 \
    WAIT_STMT;                                                                  \
    bar();                                                                      \
    LGKM0; SCHED0;                                                              \
    __builtin_amdgcn_s_setprio(1);                                              \
    _Pragma("unroll")                                                           \
    for (int m = 0; m < 4; ++m)                                                 \
    _Pragma("unroll")                                                           \
        for (int n = 0; n < NR; ++n)                                            \
            acc[(MH) * 4 + m][n] = __builtin_amdgcn_mfma_f32_16x16x32_bf16(     \
                af[m], bfr[n], acc[(MH) * 4 + m][n], 0, 0, 0);                  \
    __builtin_amdgcn_s_setprio(0);                                              \
    bar();                                                                      \
} while (0)

    // prologue: tile0 fully + tile1 {B-ks0, A-H0} (what t=-1 ph2/ph3 would do)
    stageA(0, 0, 0); stageA(0, 0, 1); stageB(0, 0, 0); stageB(0, 0, 1);
    if (NT > 1) { stageB(1, 1, 0); stageA(1, 1, 0); }
    if constexpr (BN == 256) WAITVM(4); else WAITVM(3);   // tile0 landed
    bar();

#pragma unroll 1
    for (int t = 0; t < NT; ++t) {
        const int p = t & 1;
        const char* bufp = sm + p * BUF;
        PHASE(0, 0, { if (t + 1 < NT) stageA(t + 1, p ^ 1, 1); }, {});
        PHASE(1, 0, { if (t + 1 < NT) stageB(t + 1, p ^ 1, 1); }, {});
        PHASE(0, 1, { if (t + 2 < NT) stageB(t + 2, p, 0); }, {});
        PHASE(1, 1, { if (t + 2 < NT) stageA(t + 2, p, 0); },
              { if (t + 2 < NT) { if constexpr (BN == 256) WAITVM(4); else WAITVM(3); }
                else if (t + 1 < NT) WAITVM(0); });
    }
#undef PHASE

    // epilogue: C/D layout col=lane&15, row=(lane>>4)*4+j
    const long row0 = (long)by * 256 + wr * 128 + (lane >> 4) * 4;
    const long col0 = (long)bx * BN + wc * 16 * NR + (lane & 15);
#pragma unroll
    for (int m = 0; m < 8; ++m)
#pragma unroll
        for (int n = 0; n < NR; ++n)
#pragma unroll
            for (int j = 0; j < 4; ++j) {
                const long r = row0 + m * 16 + j;
                const long c = col0 + n * 16;
                const float v = acc[m][n][j];
                if (MODE == 0) {
                    ((float*)C)[zb * sCb + r * ldc + c] = v;
                } else if (MODE == 1) {
                    ((float*)C)[zb * sCb + r * ldc + c] = v + add[zb * sAddb + r * ldadd + c];
                } else if (MODE == 2) {
                    float tt = v + bias[c];
                    float gl = 0.5f * tt * (1.0f + erff(tt * 0.70710678118654752f));
                    ((unsigned short*)C)[zb * sCb + r * ldc + c] = f2bf(gl);
                } else {
                    ((float*)C)[zb * sCb + r * ldc + c] = v + bias[c] + add[zb * sAddb + r * ldadd + c];
                }
            }
}

// ---------- LayerNorm: f32 in -> bf16 out (+ optional sum(y^2), + zero pad) ----------
__global__ __launch_bounds__(256) void ln_kernel(
    const float* __restrict__ x, const float* __restrict__ gamma, const float* __restrict__ beta,
    unsigned short* __restrict__ out, int ldout, float* qout, int pad)
{
    const int tid = threadIdx.x;
    const long row = blockIdx.x;
    float4 v = ((const float4*)(x + row * 1024))[tid];
    float s = v.x + v.y + v.z + v.w;
    float s2 = v.x * v.x + v.y * v.y + v.z * v.z + v.w * v.w;
#pragma unroll
    for (int off = 32; off; off >>= 1) {
        s  += __shfl_down(s, off);
        s2 += __shfl_down(s2, off);
    }
    __shared__ float red[12];
    const int lane = tid & 63, wid = tid >> 6;
    if (lane == 0) { red[wid] = s; red[4 + wid] = s2; }
    __syncthreads();
    s  = red[0] + red[1] + red[2] + red[3];
    s2 = red[4] + red[5] + red[6] + red[7];
    const float mu = s * (1.0f / 1024.0f);
    const float var = s2 * (1.0f / 1024.0f) - mu * mu;
    const float rs = rsqrtf(var + 1e-5f);
    const float4 g = ((const float4*)gamma)[tid];
    const float4 b = ((const float4*)beta)[tid];
    unsigned short o0 = f2bf((v.x - mu) * rs * g.x + b.x);
    unsigned short o1 = f2bf((v.y - mu) * rs * g.y + b.y);
    unsigned short o2 = f2bf((v.z - mu) * rs * g.z + b.z);
    unsigned short o3 = f2bf((v.w - mu) * rs * g.w + b.w);
    ushort4 ov; ov.x = o0; ov.y = o1; ov.z = o2; ov.w = o3;
    ((ushort4*)(out + row * (long)ldout))[tid] = ov;
    if (pad && tid < 32) out[row * (long)ldout + 1056 + tid] = 0;  // zero K-pad
    if (qout) {  // q partial = sum over d of (rounded hn)^2
        float y0 = bf2f(o0), y1 = bf2f(o1), y2 = bf2f(o2), y3 = bf2f(o3);
        float sq = y0 * y0 + y1 * y1 + y2 * y2 + y3 * y3;
#pragma unroll
        for (int off = 32; off; off >>= 1) sq += __shfl_down(sq, off);
        if (lane == 0) red[8 + wid] = sq;
        __syncthreads();
        if (tid == 0) qout[row] = red[8] + red[9] + red[10] + red[11];
    }
}

// ---------- u = hn @ L (r=32), write bf16 into z cols [1024,1056), q += |u|^2 ----------
__global__ __launch_bounds__(256) void u_kernel(
    unsigned short* __restrict__ z, const float* __restrict__ L, float* __restrict__ q)
{
    const int tid = threadIdx.x;
    const long row = blockIdx.x;
    __shared__ float hn[1024];
    __shared__ float part[8][32];
    ushort4 uv = ((const ushort4*)(z + row * 1088))[tid];
    hn[tid * 4 + 0] = bf2f(uv.x);
    hn[tid * 4 + 1] = bf2f(uv.y);
    hn[tid * 4 + 2] = bf2f(uv.z);
    hn[tid * 4 + 3] = bf2f(uv.w);
    __syncthreads();
    const int j = tid & 31, grp = tid >> 5;
    float acc = 0.f;
    const float* Lp = L + j;
#pragma unroll 4
    for (int d = grp * 128; d < grp * 128 + 128; ++d)
        acc += hn[d] * Lp[(long)d * 32];
    part[grp][j] = acc;
    __syncthreads();
    if (tid < 32) {
        float u = 0.f;
#pragma unroll
        for (int g2 = 0; g2 < 8; ++g2) u += part[g2][tid];
        unsigned short ub = f2bf(u);
        z[row * 1088 + 1024 + tid] = ub;
        float uf = bf2f(ub);
        part[0][tid] = uf * uf;
    }
    __syncthreads();
    if (tid == 0) {
        float sq = 0.f;
#pragma unroll
        for (int t2 = 0; t2 < 32; ++t2) sq += part[0][t2];
        q[row] += sq;
    }
}

// ---------- softmax over row: logits = 2*S - q_j; write P bf16 in place ----------
__global__ __launch_bounds__(256) void softmax_kernel(
    float* S, const float* qb)
{
    const int tid = threadIdx.x;
    const long i = blockIdx.x, bl = blockIdx.y;
    float* Sr = S + (bl * 2048 + i) * 2048;
    const float* qr = qb + bl * 2048;
    float l[8];
    float mx = -1e30f;
#pragma unroll
    for (int c2 = 0; c2 < 8; ++c2) {
        const int jj = tid + c2 * 256;
        l[c2] = 2.0f * Sr[jj] - qr[jj];
        mx = fmaxf(mx, l[c2]);
    }
#pragma unroll
    for (int off = 32; off; off >>= 1) mx = fmaxf(mx, __shfl_xor(mx, off));
    __shared__ float red[8];
    const int lane = tid & 63, wid = tid >> 6;
    if (lane == 0) red[wid] = mx;
    __syncthreads();
    mx = fmaxf(fmaxf(red[0], red[1]), fmaxf(red[2], red[3]));
    float sum = 0.f;
#pragma unroll
    for (int c2 = 0; c2 < 8; ++c2) { l[c2] = __expf(l[c2] - mx); sum += l[c2]; }
#pragma unroll
    for (int off = 32; off; off >>= 1) sum += __shfl_xor(sum, off);
    if (lane == 0) red[4 + wid] = sum;
    __syncthreads();
    sum = red[4] + red[5] + red[6] + red[7];
    const float inv = 1.0f / sum;
    unsigned short* Pr = (unsigned short*)S + (bl * 2048 + i) * 4096;  // row stride 8192B
#pragma unroll
    for (int c2 = 0; c2 < 8; ++c2)
        Pr[tid + c2 * 256] = f2bf(l[c2] * inv);
}

// ---------- Vt[b][n][k] = z[b][k][n] (hn part only), bf16 ----------
__global__ __launch_bounds__(256) void transpose_v_kernel(
    const unsigned short* __restrict__ z, unsigned short* __restrict__ Vt, long sVtb)
{
    __shared__ unsigned short t[32][33];
    const int tid = threadIdx.x;
    const int tx = tid & 31, ty = tid >> 5;
    const long b = blockIdx.z;
    const long k0 = (long)blockIdx.x * 32, n0 = (long)blockIdx.y * 32;
#pragma unroll
    for (int r = 0; r < 32; r += 8)
        t[r + ty][tx] = z[(b * 2048 + k0 + r + ty) * 1088 + n0 + tx];
    __syncthreads();
#pragma unroll
    for (int r = 0; r < 32; r += 8)
        Vt[b * sVtb + (n0 + r + ty) * 2048 + k0 + tx] = t[tx][r + ty];
}

// ---------- Wt[c][r] = bf16(W[r][c]) ----------
__global__ __launch_bounds__(256) void cast_transpose_kernel(
    const float* __restrict__ W, unsigned short* __restrict__ Wt, int rows, int cols)
{
    __shared__ float t[32][33];
    const int tid = threadIdx.x;
    const int tx = tid & 31, ty = tid >> 5;
    const long r0 = (long)blockIdx.y * 32, c0 = (long)blockIdx.x * 32;
#pragma unroll
    for (int r = 0; r < 32; r += 8)
        t[r + ty][tx] = W[(r0 + r + ty) * (long)cols + c0 + tx];
    __syncthreads();
#pragma unroll
    for (int r = 0; r < 32; r += 8)
        Wt[(c0 + r + ty) * (long)rows + r0 + tx] = f2bf(t[tx][r + ty]);
}

// ---------- host ----------
// Workspace plan (>= 89.2 MB measured-safe):
//   q    : 32 KB
//   pool : attention overlay  Vt 16.8 | Smat 67.1             (= 83.9 MB)
//          MLP overlay        W1t 8.4 | W2t 8.4 | hm 16.8 | hid 67.1/c
//   z (17.8 MB) lives in d_out (33.5 MB) — dead before PV overwrites it.
extern "C" void kernel_launch(void* const* d_in, const int* in_sizes, int n_in,
                              void* d_out, int out_size, void* d_ws, size_t ws_size,
                              hipStream_t stream)
{
    const float* x   = (const float*)d_in[0];
    const float* L   = (const float*)d_in[1];
    const float* W1  = (const float*)d_in[2];
    const float* b1  = (const float*)d_in[3];
    const float* W2  = (const float*)d_in[4];
    const float* b2  = (const float*)d_in[5];
    const float* g1  = (const float*)d_in[6];
    const float* be1 = (const float*)d_in[7];
    const float* g2  = (const float*)d_in[8];
    const float* be2 = (const float*)d_in[9];
    float* out = (float*)d_out;
    unsigned short* z = (unsigned short*)d_out;     // 8192 x 1088 bf16 in d_out

    char* wsp = (char*)d_ws;
    float* q = (float*)wsp;                          // 32 KB
    char* pool = wsp + 32768;
    // attention overlay
    unsigned short* Vt   = (unsigned short*)pool;                      // 4 x 1024 x 2048 bf16
    float*          Smat = (float*)(pool + 16777216);                  // 4 x 2048 x 2048 f32
    // MLP overlay (valid after PV has consumed Vt/Smat)
    unsigned short* W1t = (unsigned short*)pool;                       // 4096 x 1024 bf16
    unsigned short* W2t = (unsigned short*)(pool + 8388608);           // 1024 x 4096 bf16
    unsigned short* hm  = (unsigned short*)(pool + 16777216);          // 8192 x 1024 bf16
    unsigned short* hid = (unsigned short*)(pool + 33554432);          // 8192 x 4096 bf16 (or /2)
    const bool fullMLP = ws_size >= (size_t)32768 + 100663296 + 65536;

    // LN1 -> z[:,0:1024], q = |hn|^2, zero pad cols 1056:1088
    ln_kernel<<<8192, 256, 0, stream>>>(x, g1, be1, z, 1088, q, 1);
    // u = hn@L -> z[:,1024:1056], q += |u|^2
    u_kernel<<<8192, 256, 0, stream>>>(z, L, q);

    // ---- attention, all 4 batches in parallel ----
    transpose_v_kernel<<<dim3(64, 32, 4), 256, 0, stream>>>(z, Vt, (long)1024 * 2048);
    gemm8q<256, 0, 1><<<dim3(8, 8, 4), 512, 0, stream>>>(
        z, 1088, (long)2048 * 1088,
        z, 1088, (long)2048 * 1088,
        Smat, 2048, (long)2048 * 2048,
        nullptr, 0, 0, nullptr, 1088);
    softmax_kernel<<<dim3(2048, 4), 256, 0, stream>>>(Smat, q);
    gemm8q<128, 1, 1><<<dim3(8, 8, 4), 512, 0, stream>>>(
        (const unsigned short*)Smat, 4096, (long)2048 * 4096,
        Vt, 2048, (long)1024 * 2048,
        out, 1024, (long)2048 * 1024,
        x, 1024, (long)2048 * 1024,
        nullptr, 2048);

    // ---- MLP ----
    cast_transpose_kernel<<<dim3(128, 32), 256, 0, stream>>>(W1, W1t, 1024, 4096);
    cast_transpose_kernel<<<dim3(32, 128), 256, 0, stream>>>(W2, W2t, 4096, 1024);
    ln_kernel<<<8192, 256, 0, stream>>>(out, g2, be2, hm, 1024, nullptr, 0);
    if (fullMLP) {
        gemm8q<256, 2, 0><<<dim3(16, 32, 1), 512, 0, stream>>>(
            hm, 1024, 0, W1t, 1024, 0,
            hid, 4096, 0, nullptr, 0, 0, b1, 1024);
        gemm8q<128, 3, 0><<<dim3(8, 32, 1), 512, 0, stream>>>(
            hid, 4096, 0, W2t, 4096, 0,
            out, 1024, 0, out, 1024, 0, b2, 4096);
    } else {
        for (int c = 0; c < 2; ++c) {
            const unsigned short* hmc = hm + (size_t)c * 4096 * 1024;
            float* oc = out + (size_t)c * 4096 * 1024;
            gemm8q<256, 2, 0><<<dim3(16, 16, 1), 512, 0, stream>>>(
                hmc, 1024, 0, W1t, 1024, 0,
                hid, 4096, 0, nullptr, 0, 0, b1, 1024);
            gemm8q<128, 3, 0><<<dim3(8, 16, 1), 512, 0, stream>>>(
                hid, 4096, 0, W2t, 4096, 0,
                oc, 1024, 0, oc, 1024, 0, b2, 4096);
        }
    }
}